// Round 15
// baseline (224.739 us; speedup 1.0000x reference)
//
#include <hip/hip_runtime.h>
#include <hip/hip_bf16.h>
#include <math.h>

#define BATCH 2
#define NPTS  8192
#define CIN   32
#define HID   128
#define COUT  64
#define EIN   67
#define KNN   16

#define TILE  1024   // fallback knn candidate tile
#define CAP   128    // survivor cap per point
#define KMARGIN 1e-3f

typedef unsigned short u16;
typedef unsigned long long u64;
typedef __attribute__((ext_vector_type(8))) short bf16x8;  // MFMA A/B frag
typedef __attribute__((ext_vector_type(4))) float f32x4;   // MFMA C/D frag

__device__ __forceinline__ u16 f2b(float f) {   // RNE fp32->bf16
    unsigned u = __float_as_uint(f);
    return (u16)((u + 0x7FFFu + ((u >> 16) & 1u)) >> 16);
}
__device__ __forceinline__ unsigned pk2(float a, float b) {
    return (unsigned)f2b(a) | ((unsigned)f2b(b) << 16);
}
__device__ __forceinline__ float gelu_t(float x) {
    float u = 1.5957691216057308f * (x + 0.044715f * x * x * x);
    float ex = __expf(u);
    return x * ex / (ex + 1.0f);
}

// ============== prep: verts -> float4 {x,y,z,sq} in d_ws ==============
__global__ void prep_kernel(const float* __restrict__ verts, float4* __restrict__ pv) {
    int i = blockIdx.x * blockDim.x + threadIdx.x;
    if (i >= BATCH * NPTS) return;
    float x = verts[3 * i], y = verts[3 * i + 1], z = verts[3 * i + 2];
    float sq = __fadd_rn(__fadd_rn(__fmul_rn(x, x), __fmul_rn(y, y)), __fmul_rn(z, z));
    pv[i] = make_float4(x, y, z, sq);
}

// ============== KNN v7: knn6 + unroll-4 scans (output provably identical) ==============
__global__ __launch_bounds__(256, 4) void knn7_kernel(const float4* __restrict__ pv,
                                                      int* __restrict__ nbr_out_rows) {
    __shared__ float4 minv4[4][64];
    __shared__ float  bufD[4][4][CAP];
    __shared__ int    bufJ[4][4][CAP];

    const int tid = threadIdx.x, lane = tid & 63, wv = tid >> 6;
    const int pt0 = (blockIdx.x * 4 + wv) * 4;
    const int b = pt0 >> 13, i0 = pt0 & (NPTS - 1);
    const float4* P = pv + (size_t)b * NPTS;

    float4 sp[4];
    float ax[4], ay[4], az[4];
#pragma unroll
    for (int p = 0; p < 4; ++p) {
        sp[p] = P[i0 + p];
        ax[p] = -2.0f * sp[p].x; ay[p] = -2.0f * sp[p].y; az[p] = -2.0f * sp[p].z;
    }

    // ---- pass 1: fast per-lane min over first 4096 cands, 4 loads in flight ----
    float mn[4] = {INFINITY, INFINITY, INFINITY, INFINITY};
    for (int t = 0; t < 16; ++t) {
        float4 c0 = P[t * 256 + lane];
        float4 c1 = P[t * 256 + 64 + lane];
        float4 c2 = P[t * 256 + 128 + lane];
        float4 c3 = P[t * 256 + 192 + lane];
#pragma unroll
        for (int p = 0; p < 4; ++p) {
            float f0 = __fmaf_rn(ax[p], c0.x, __fmaf_rn(ay[p], c0.y, __fmaf_rn(az[p], c0.z, c0.w)));
            float f1 = __fmaf_rn(ax[p], c1.x, __fmaf_rn(ay[p], c1.y, __fmaf_rn(az[p], c1.z, c1.w)));
            float f2 = __fmaf_rn(ax[p], c2.x, __fmaf_rn(ay[p], c2.y, __fmaf_rn(az[p], c2.z, c2.w)));
            float f3 = __fmaf_rn(ax[p], c3.x, __fmaf_rn(ay[p], c3.y, __fmaf_rn(az[p], c3.z, c3.w)));
            mn[p] = fminf(fminf(fminf(mn[p], f0), fminf(f1, f2)), f3);   // exact: min reassoc-safe
        }
    }

    // ---- tau_p = 16th smallest lane-min + margin (rank-select) ----
    minv4[wv][lane] = make_float4(mn[0], mn[1], mn[2], mn[3]);
    int rk[4] = {0, 0, 0, 0};
    for (int mm = 0; mm < 64; ++mm) {
        float4 v = minv4[wv][mm];
        rk[0] += (v.x < mn[0]) || (v.x == mn[0] && mm < lane);
        rk[1] += (v.y < mn[1]) || (v.y == mn[1] && mm < lane);
        rk[2] += (v.z < mn[2]) || (v.z == mn[2] && mm < lane);
        rk[3] += (v.w < mn[3]) || (v.w == mn[3] && mm < lane);
    }
    float tau[4];
#pragma unroll
    for (int p = 0; p < 4; ++p) {
        u64 bal = __ballot(rk[p] == 15);
        int srcl = __ffsll(bal) - 1;
        tau[p] = __shfl(mn[p], srcl, 64) + KMARGIN;
    }

    // ---- pass 2: full scan (unroll 4), fast filter, two-level skip, compact ----
    int base[4] = {0, 0, 0, 0};
    for (int t = 0; t < 32; ++t) {
        float4 c[4];
#pragma unroll
        for (int k = 0; k < 4; ++k) c[k] = P[t * 256 + k * 64 + lane];
        bool pr[4][4];
        bool anyl = false;
#pragma unroll
        for (int k = 0; k < 4; ++k)
#pragma unroll
            for (int p = 0; p < 4; ++p) {
                float f = __fmaf_rn(ax[p], c[k].x,
                          __fmaf_rn(ay[p], c[k].y,
                          __fmaf_rn(az[p], c[k].z, c[k].w)));
                pr[k][p] = (f <= tau[p]);
                anyl |= pr[k][p];
            }
        if (__ballot(anyl) == 0ull) continue;
#pragma unroll
        for (int k = 0; k < 4; ++k) {
            u64 anyk = __ballot(pr[k][0] | pr[k][1] | pr[k][2] | pr[k][3]);
            if (anyk == 0ull) continue;
            int j = t * 256 + k * 64 + lane;
#pragma unroll
            for (int p = 0; p < 4; ++p) {
                u64 mk = __ballot(pr[k][p]);
                if (mk != 0ull) {
                    if (pr[k][p]) {
                        int pos = base[p] + (int)__popcll(mk & ((1ull << lane) - 1ull));
                        if (pos < CAP) bufJ[wv][p][pos] = j;
                    }
                    base[p] += (int)__popcll(mk);
                }
            }
        }
    }

    // ---- exact rescore + (d,j)-lex rank-select per point ----
#pragma unroll
    for (int p = 0; p < 4; ++p) {
        int ns = base[p]; ns = (ns > CAP) ? CAP : ns;   // >= 16 guaranteed
        float dloc[2]; int jloc[2];
#pragma unroll
        for (int slot = 0; slot < 2; ++slot) {
            int sidx = slot * 64 + lane;
            bool act = sidx < ns;
            int js = act ? bufJ[wv][p][sidx] : 0;
            float4 cc = P[js];
            float dot = __fmul_rn(sp[p].x, cc.x);
            dot = __fmaf_rn(sp[p].y, cc.y, dot);
            dot = __fmaf_rn(sp[p].z, cc.z, dot);
            float d = __fsub_rn(__fadd_rn(sp[p].w, cc.w), __fmul_rn(2.0f, dot));
            if (act) bufD[wv][p][sidx] = d;
            dloc[slot] = d; jloc[slot] = js;
        }
        int r0 = 0, r1 = 0;
        for (int mm = 0; mm < ns; ++mm) {
            float dm = bufD[wv][p][mm]; int jm = bufJ[wv][p][mm];
            r0 += (dm < dloc[0]) || (dm == dloc[0] && jm < jloc[0]);
            r1 += (dm < dloc[1]) || (dm == dloc[1] && jm < jloc[1]);
        }
        if (lane < ns && r0 < KNN)
            nbr_out_rows[(size_t)(pt0 + p) * 64 + r0] = jloc[0];
        if (64 + lane < ns && r1 < KNN)
            nbr_out_rows[(size_t)(pt0 + p) * 64 + r1] = jloc[1];
    }
}

// ============== KNN fallback (used only if ws too small) ==============
__global__ __launch_bounds__(256) void knn_kernel(const float* __restrict__ verts,
                                                  int* nbr_out_rows) {
    __shared__ float4 tilebuf[TILE];
    __shared__ float  bufD[4][CAP];
    __shared__ int    bufJ[4][CAP];

    const int tid = threadIdx.x, lane = tid & 63, wv = tid >> 6;
    const int pt = blockIdx.x * 4 + wv;
    const int b = pt >> 13, i = pt & (NPTS - 1);
    const float* vb = verts + (size_t)b * NPTS * 3;

    const float xi = vb[3 * i], yi = vb[3 * i + 1], zi = vb[3 * i + 2];
    const float sqi = __fadd_rn(__fadd_rn(__fmul_rn(xi, xi), __fmul_rn(yi, yi)),
                                __fmul_rn(zi, zi));

    float m_d = INFINITY;
    for (int t = 0; t < NPTS / TILE; ++t) {
        __syncthreads();
        for (int s = 0; s < TILE / 256; ++s) {
            int p = t * TILE + s * 256 + tid;
            float px = vb[3 * p], py = vb[3 * p + 1], pz = vb[3 * p + 2];
            float sq = __fadd_rn(__fadd_rn(__fmul_rn(px, px), __fmul_rn(py, py)),
                                 __fmul_rn(pz, pz));
            tilebuf[s * 256 + tid] = make_float4(px, py, pz, sq);
        }
        __syncthreads();
        for (int it = 0; it < TILE / 64; ++it) {
            float4 c = tilebuf[it * 64 + lane];
            float dot = __fmul_rn(xi, c.x);
            dot = __fmaf_rn(yi, c.y, dot);
            dot = __fmaf_rn(zi, c.z, dot);
            float d = __fsub_rn(__fadd_rn(sqi, c.w), __fmul_rn(2.0f, dot));
            m_d = fminf(m_d, d);
        }
    }
    __shared__ float minv[4][64];
    minv[wv][lane] = m_d;
    __syncthreads();
    int rnk = 0;
    for (int mm = 0; mm < 64; ++mm) {
        float vm = minv[wv][mm];
        rnk += (vm < m_d) || (vm == m_d && mm < lane);
    }
    u64 bal = __ballot(rnk == 15);
    float tau = __shfl(m_d, __ffsll(bal) - 1, 64);

    int base = 0;
    for (int t = 0; t < NPTS / TILE; ++t) {
        __syncthreads();
        for (int s = 0; s < TILE / 256; ++s) {
            int p = t * TILE + s * 256 + tid;
            float px = vb[3 * p], py = vb[3 * p + 1], pz = vb[3 * p + 2];
            float sq = __fadd_rn(__fadd_rn(__fmul_rn(px, px), __fmul_rn(py, py)),
                                 __fmul_rn(pz, pz));
            tilebuf[s * 256 + tid] = make_float4(px, py, pz, sq);
        }
        __syncthreads();
        for (int it = 0; it < TILE / 64; ++it) {
            int jl = it * 64 + lane;
            float4 c = tilebuf[jl];
            float dot = __fmul_rn(xi, c.x);
            dot = __fmaf_rn(yi, c.y, dot);
            dot = __fmaf_rn(zi, c.z, dot);
            float d = __fsub_rn(__fadd_rn(sqi, c.w), __fmul_rn(2.0f, dot));
            bool pred = (d <= tau);
            u64 mask = __ballot(pred);
            if (pred) {
                int pos = base + (int)__popcll(mask & ((1ull << lane) - 1ull));
                if (pos < CAP) { bufD[wv][pos] = d; bufJ[wv][pos] = t * TILE + jl; }
            }
            base += (int)__popcll(mask);
        }
    }
    int ns = (base > CAP) ? CAP : base;
    __syncthreads();
#pragma unroll
    for (int slot = 0; slot < 2; ++slot) {
        int sidx = slot * 64 + lane;
        if (sidx < ns) {
            float ds = bufD[wv][sidx];
            int   js = bufJ[wv][sidx];
            int rank = 0;
            for (int mm = 0; mm < ns; ++mm) {
                float dm = bufD[wv][mm];
                int   jm = bufJ[wv][mm];
                rank += (dm < ds) || (dm == ds && jm < js);
            }
            if (rank < KNN) nbr_out_rows[(size_t)pt * 64 + rank] = js;
        }
    }
}

// ============ edge4: barrier-free MFMA edge MLP + mean + point MLP ============
// VERBATIM round-11 green kernel. (256,2): no spill; (256,3) spilled ~250 MB.
__global__ __launch_bounds__(256, 2) void edge4_kernel(
    const float* __restrict__ verts, const float* __restrict__ feats,
    const float* __restrict__ W1, const float* __restrict__ b1,
    const float* __restrict__ g1, const float* __restrict__ be1,
    const float* __restrict__ W2, const float* __restrict__ b2,
    const float* __restrict__ Wo1, const float* __restrict__ bo1,
    const float* __restrict__ go_, const float* __restrict__ beo,
    const float* __restrict__ Wo2, const float* __restrict__ bo2,
    float* out)   // rows hold knn idx on entry; final output on exit
{
    __shared__ u16 EPw[4][4][64][8];    // 16 KB: per-wave E/P A-frag region
    __shared__ u16 W1F[3][8][64][8];    // 24 KB (phase2: Wo1 frags in kt 0..1)
    __shared__ float b1s[HID], g1s[HID], be1s[HID];
    __shared__ float b2s[COUT];
    __shared__ float meansh[16][68];    // 4.25 KB; phase2: staging for out rows

    const int tid  = threadIdx.x;
    const int lane = tid & 63, wv = tid >> 6;
    const int quad = lane >> 4, n16 = lane & 15;

    // ---- stage W1 as B-fragments ----
    for (int s = tid; s < 3 * 8 * 64; s += 256) {
        int kt = s >> 9, nt = (s >> 6) & 7, ln = s & 63;
        int q = ln >> 4, nn = ln & 15;
        int col = nt * 16 + nn;
        union { bf16x8 v; unsigned u[4]; } pk;
#pragma unroll
        for (int jj = 0; jj < 4; ++jj) {
            int k0 = kt * 32 + q * 8 + jj * 2;
            float a  = (k0     < EIN) ? W1[(size_t)k0 * HID + col]       : 0.0f;
            float bq = (k0 + 1 < EIN) ? W1[(size_t)(k0 + 1) * HID + col] : 0.0f;
            pk.u[jj] = pk2(a, bq);
        }
        *(bf16x8*)&W1F[kt][nt][ln][0] = pk.v;
    }
    if (tid < HID) { b1s[tid] = b1[tid]; g1s[tid] = g1[tid]; be1s[tid] = be1[tid]; }
    if (tid < COUT) b2s[tid] = b2[tid];

    // ---- W2 as B-fragments in registers (64 VGPR) ----
    bf16x8 w2r[4][4];
#pragma unroll
    for (int kt2 = 0; kt2 < 4; ++kt2)
#pragma unroll
        for (int nt2 = 0; nt2 < 4; ++nt2) {
            union { bf16x8 v; unsigned u[4]; } pk;
#pragma unroll
            for (int jj = 0; jj < 4; ++jj) {
                int k0 = kt2 * 32 + quad * 8 + jj * 2;
                int o = nt2 * 16 + n16;
                pk.u[jj] = pk2(W2[(size_t)k0 * COUT + o],
                               W2[(size_t)(k0 + 1) * COUT + o]);
            }
            w2r[kt2][nt2] = pk.v;
        }
    __syncthreads();   // W1F + biases visible to all waves

    const int ptb = blockIdx.x * 16;
    const int bb  = ptb >> 13;
    const float* fb  = feats + (size_t)bb * NPTS * CIN;
    const float* vbk = verts + (size_t)bb * NPTS * 3;
    const int ptw = ptb + wv * 4;              // this wave's 4 points
    const int ipw = ptw & (NPTS - 1);

    // hoisted LN operands (point-independent)
    float b1v[8], g1v[8], bev[8];
#pragma unroll
    for (int nt = 0; nt < 8; ++nt) {
        b1v[nt] = b1s[nt * 16 + n16];
        g1v[nt] = g1s[nt * 16 + n16];
        bev[nt] = be1s[nt * 16 + n16];
    }

    const int k16 = lane & 15;
    const int qq  = lane >> 4;

    int jnv[4];
#pragma unroll
    for (int pp = 0; pp < 4; ++pp)
        jnv[pp] = ((const int*)out)[(size_t)(ptw + pp) * 64 + k16];

#pragma unroll
    for (int pp = 0; pp < 4; ++pp) {
        const int jn  = jnv[pp];
        const int ipn = ipw + pp;

        // ---- gather + pack + store E (3 b128 per lane, wave-local) ----
        {
            const float* nsrc = fb + (size_t)jn * CIN + qq * 8;
            float4 nA = *(const float4*)nsrc, nB = *(const float4*)(nsrc + 4);
            const float* ssrc = fb + (size_t)ipn * CIN + qq * 8;
            float4 sA = *(const float4*)ssrc, sB = *(const float4*)(ssrc + 4);

            union { bf16x8 v; unsigned u[4]; } e0, e1, e2;
            e0.u[0] = pk2(nA.x, nA.y); e0.u[1] = pk2(nA.z, nA.w);
            e0.u[2] = pk2(nB.x, nB.y); e0.u[3] = pk2(nB.z, nB.w);
            e1.u[0] = pk2(sA.x, sA.y); e1.u[1] = pk2(sA.z, sA.w);
            e1.u[2] = pk2(sB.x, sB.y); e1.u[3] = pk2(sB.z, sB.w);
            e2.u[0] = e2.u[1] = e2.u[2] = e2.u[3] = 0u;
            if (qq == 0) {
                float rx = vbk[3 * jn]     - vbk[3 * ipn];
                float ry = vbk[3 * jn + 1] - vbk[3 * ipn + 1];
                float rz = vbk[3 * jn + 2] - vbk[3 * ipn + 2];
                e2.u[0] = pk2(rx, ry); e2.u[1] = pk2(rz, 0.0f);
            }
            *(bf16x8*)&EPw[wv][0][lane][0] = e0.v;
            *(bf16x8*)&EPw[wv][1][lane][0] = e1.v;
            *(bf16x8*)&EPw[wv][2][lane][0] = e2.v;
        }

        // ---- GEMM1: D1[16 edges][128 hid] ----
        f32x4 acc[8];
#pragma unroll
        for (int nt = 0; nt < 8; ++nt) acc[nt] = (f32x4){0.f, 0.f, 0.f, 0.f};
#pragma unroll
        for (int kt = 0; kt < 3; ++kt) {
            bf16x8 a = *(bf16x8*)&EPw[wv][kt][lane][0];
#pragma unroll
            for (int nt = 0; nt < 8; ++nt) {
                bf16x8 bfr = *(bf16x8*)&W1F[kt][nt][lane][0];
                acc[nt] = __builtin_amdgcn_mfma_f32_16x16x32_bf16(a, bfr, acc[nt], 0, 0, 0);
            }
        }

        // ---- bias + LN (16-lane groups) ----
        float s1[4] = {0,0,0,0}, s2[4] = {0,0,0,0};
#pragma unroll
        for (int nt = 0; nt < 8; ++nt)
#pragma unroll
            for (int r = 0; r < 4; ++r) {
                float x = acc[nt][r] + b1v[nt];
                s1[r] += x; s2[r] += x * x;
            }
#pragma unroll
        for (int r = 0; r < 4; ++r) {
#pragma unroll
            for (int off = 1; off < 16; off <<= 1) {
                s1[r] += __shfl_xor(s1[r], off, 64);
                s2[r] += __shfl_xor(s2[r], off, 64);
            }
        }
        float mu[4], rs[4];
#pragma unroll
        for (int r = 0; r < 4; ++r) {
            mu[r] = s1[r] * (1.0f / HID);
            float var = s2[r] * (1.0f / HID) - mu[r] * mu[r];
            rs[r] = rsqrtf(var + 1e-5f);
        }

        // ---- GELU + pack into A-frag layout (P over EPw[wv]) ----
#pragma unroll
        for (int nt = 0; nt < 8; ++nt) {
            int kt2 = nt >> 1;
            int q2  = (nt * 2 + (n16 >> 3)) & 3;
            int jj  = n16 & 7;
#pragma unroll
            for (int r = 0; r < 4; ++r) {
                float x  = acc[nt][r] + b1v[nt];
                float xn = (x - mu[r]) * rs[r] * g1v[nt] + bev[nt];
                EPw[wv][kt2][quad * 4 + r + 16 * q2][jj] = (u16)f2b(gelu_t(xn));
            }
        }

        // ---- GEMM2: D2[16 edges][64 out] ----
        f32x4 acc2[4];
#pragma unroll
        for (int nt2 = 0; nt2 < 4; ++nt2) acc2[nt2] = (f32x4){0.f, 0.f, 0.f, 0.f};
#pragma unroll
        for (int kt2 = 0; kt2 < 4; ++kt2) {
            bf16x8 a2 = *(bf16x8*)&EPw[wv][kt2][lane][0];
#pragma unroll
            for (int nt2 = 0; nt2 < 4; ++nt2)
                acc2[nt2] = __builtin_amdgcn_mfma_f32_16x16x32_bf16(a2, w2r[kt2][nt2], acc2[nt2], 0, 0, 0);
        }

        // ---- mean over 16 edges (+b2) -> meansh ----
#pragma unroll
        for (int nt2 = 0; nt2 < 4; ++nt2) {
            float cs = acc2[nt2][0] + acc2[nt2][1] + acc2[nt2][2] + acc2[nt2][3];
            cs += __shfl_xor(cs, 16, 64);
            cs += __shfl_xor(cs, 32, 64);
            if (quad == 0) {
                int o = nt2 * 16 + n16;
                meansh[wv * 4 + pp][o] = cs * (1.0f / KNN) + b2s[o];
            }
        }
    }

    // ======== phase 2: point MLP (MFMA) for the block's 16 points ========
    __syncthreads();   // all means written; safe to overlay W1F/biases

    for (int s = tid; s < 2 * 8 * 64; s += 256) {   // Wo1 B-frags (K=64)
        int kt = s >> 9, nt = (s >> 6) & 7, ln = s & 63;
        int q = ln >> 4, nn = ln & 15;
        int col = nt * 16 + nn;
        union { bf16x8 v; unsigned u[4]; } pk;
#pragma unroll
        for (int jj = 0; jj < 4; ++jj) {
            int k0 = kt * 32 + q * 8 + jj * 2;
            pk.u[jj] = pk2(Wo1[(size_t)k0 * HID + col],
                           Wo1[(size_t)(k0 + 1) * HID + col]);
        }
        *(bf16x8*)&W1F[kt][nt][ln][0] = pk.v;
    }
    if (tid < HID) { b1s[tid] = bo1[tid]; g1s[tid] = go_[tid]; be1s[tid] = beo[tid]; }
    if (tid < COUT) b2s[tid] = bo2[tid];
#pragma unroll
    for (int kt2 = 0; kt2 < 4; ++kt2)
#pragma unroll
        for (int nt2 = 0; nt2 < 4; ++nt2) {
            union { bf16x8 v; unsigned u[4]; } pk;
#pragma unroll
            for (int jj = 0; jj < 4; ++jj) {
                int k0 = kt2 * 32 + quad * 8 + jj * 2;
                int o = nt2 * 16 + n16;
                pk.u[jj] = pk2(Wo2[(size_t)k0 * COUT + o],
                               Wo2[(size_t)(k0 + 1) * COUT + o]);
            }
            w2r[kt2][nt2] = pk.v;
        }
    __syncthreads();

    if (wv == 0) {
        bf16x8 af[2];
#pragma unroll
        for (int kt = 0; kt < 2; ++kt) {
            const float* mrow = &meansh[n16][kt * 32 + quad * 8];
            float4 A = *(const float4*)mrow, B4 = *(const float4*)(mrow + 4);
            union { bf16x8 v; unsigned u[4]; } pk;
            pk.u[0] = pk2(A.x, A.y); pk.u[1] = pk2(A.z, A.w);
            pk.u[2] = pk2(B4.x, B4.y); pk.u[3] = pk2(B4.z, B4.w);
            af[kt] = pk.v;
        }

        f32x4 acc[8];
#pragma unroll
        for (int nt = 0; nt < 8; ++nt) acc[nt] = (f32x4){0.f, 0.f, 0.f, 0.f};
#pragma unroll
        for (int kt = 0; kt < 2; ++kt)
#pragma unroll
            for (int nt = 0; nt < 8; ++nt) {
                bf16x8 bfr = *(bf16x8*)&W1F[kt][nt][lane][0];
                acc[nt] = __builtin_amdgcn_mfma_f32_16x16x32_bf16(af[kt], bfr, acc[nt], 0, 0, 0);
            }

        float pb1[8], pg1[8], pbe[8];
#pragma unroll
        for (int nt = 0; nt < 8; ++nt) {
            pb1[nt] = b1s[nt * 16 + n16];
            pg1[nt] = g1s[nt * 16 + n16];
            pbe[nt] = be1s[nt * 16 + n16];
        }
        float s1[4] = {0,0,0,0}, s2[4] = {0,0,0,0};
#pragma unroll
        for (int nt = 0; nt < 8; ++nt)
#pragma unroll
            for (int r = 0; r < 4; ++r) {
                float x = acc[nt][r] + pb1[nt];
                s1[r] += x; s2[r] += x * x;
            }
#pragma unroll
        for (int r = 0; r < 4; ++r) {
#pragma unroll
            for (int off = 1; off < 16; off <<= 1) {
                s1[r] += __shfl_xor(s1[r], off, 64);
                s2[r] += __shfl_xor(s2[r], off, 64);
            }
        }
#pragma unroll
        for (int nt = 0; nt < 8; ++nt) {
            int kt2 = nt >> 1;
            int q2  = (nt * 2 + (n16 >> 3)) & 3;
            int jj  = n16 & 7;
#pragma unroll
            for (int r = 0; r < 4; ++r) {
                float mu = s1[r] * (1.0f / HID);
                float var = s2[r] * (1.0f / HID) - mu * mu;
                float rs = rsqrtf(var + 1e-5f);
                float x  = acc[nt][r] + pb1[nt];
                float xn = (x - mu) * rs * pg1[nt] + pbe[nt];
                EPw[0][kt2][quad * 4 + r + 16 * q2][jj] = (u16)f2b(gelu_t(xn));
            }
        }

        f32x4 acc2[4];
#pragma unroll
        for (int nt2 = 0; nt2 < 4; ++nt2) acc2[nt2] = (f32x4){0.f, 0.f, 0.f, 0.f};
#pragma unroll
        for (int kt2 = 0; kt2 < 4; ++kt2) {
            bf16x8 a2 = *(bf16x8*)&EPw[0][kt2][lane][0];
#pragma unroll
            for (int nt2 = 0; nt2 < 4; ++nt2)
                acc2[nt2] = __builtin_amdgcn_mfma_f32_16x16x32_bf16(a2, w2r[kt2][nt2], acc2[nt2], 0, 0, 0);
        }

        // stage final rows into meansh (means fully consumed by af above)
#pragma unroll
        for (int nt2 = 0; nt2 < 4; ++nt2) {
            int o = nt2 * 16 + n16;
#pragma unroll
            for (int r = 0; r < 4; ++r)
                meansh[quad * 4 + r][o] = acc2[nt2][r] + b2s[o];
        }
    }
    __syncthreads();

    // coalesced float4 store: thread -> (point = tid>>4, 4 channels)
    {
        int p = tid >> 4, c = (tid & 15) * 4;
        float4 v = *(const float4*)&meansh[p][c];
        *(float4*)&out[(size_t)(ptb + p) * 64 + c] = v;
    }
}

extern "C" void kernel_launch(void* const* d_in, const int* in_sizes, int n_in,
                              void* d_out, int out_size, void* d_ws, size_t ws_size,
                              hipStream_t stream) {
    const float* verts = (const float*)d_in[0];
    const float* feats = (const float*)d_in[1];
    const float* W1  = (const float*)d_in[2];
    const float* b1  = (const float*)d_in[3];
    const float* g1  = (const float*)d_in[4];
    const float* be1 = (const float*)d_in[5];
    const float* W2  = (const float*)d_in[6];
    const float* b2  = (const float*)d_in[7];
    const float* Wo1 = (const float*)d_in[8];
    const float* bo1 = (const float*)d_in[9];
    const float* go_ = (const float*)d_in[10];
    const float* beo = (const float*)d_in[11];
    const float* Wo2 = (const float*)d_in[12];
    const float* bo2 = (const float*)d_in[13];
    float* out = (float*)d_out;

    (void)in_sizes; (void)n_in; (void)out_size;

    const size_t pv_bytes = (size_t)BATCH * NPTS * sizeof(float4);  // 256 KB
    if (ws_size >= pv_bytes) {
        float4* pv = (float4*)d_ws;
        prep_kernel<<<(BATCH * NPTS + 255) / 256, 256, 0, stream>>>(verts, pv);
        knn7_kernel<<<(BATCH * NPTS) / 16, 256, 0, stream>>>(pv, (int*)out);
    } else {
        knn_kernel<<<(BATCH * NPTS) / 4, 256, 0, stream>>>(verts, (int*)out);
    }
    edge4_kernel<<<(BATCH * NPTS) / 16, 256, 0, stream>>>(
        verts, feats, W1, b1, g1, be1, W2, b2,
        Wo1, bo1, go_, beo, Wo2, bo2, out);
}

// Round 16
// 210.091 us; speedup vs baseline: 1.0697x; 1.0697x over previous
//
#include <hip/hip_runtime.h>
#include <hip/hip_bf16.h>
#include <math.h>

#define BATCH 2
#define NPTS  8192
#define CIN   32
#define HID   128
#define COUT  64
#define EIN   67
#define KNN   16

#define TILE  1024   // fallback knn candidate tile
#define CAP   128    // survivor cap per point
#define KMARGIN 1e-3f

typedef unsigned short u16;
typedef unsigned long long u64;
typedef __attribute__((ext_vector_type(8))) short bf16x8;  // MFMA A/B frag
typedef __attribute__((ext_vector_type(4))) float f32x4;   // MFMA C/D frag

#if defined(__has_builtin)
#if __has_builtin(__builtin_amdgcn_rcpf)
#define USE_RCPF 1
#endif
#endif

__device__ __forceinline__ u16 f2b(float f) {   // RNE fp32->bf16
    unsigned u = __float_as_uint(f);
    return (u16)((u + 0x7FFFu + ((u >> 16) & 1u)) >> 16);
}
__device__ __forceinline__ unsigned pk2(float a, float b) {
    return (unsigned)f2b(a) | ((unsigned)f2b(b) << 16);
}
__device__ __forceinline__ float gelu_t(float x) {
    // tanh-approx GELU via x * e^u/(e^u+1), u = 1.59577(x + 0.044715 x^3)
    // rcpf: <=1 ulp on (ex+1) in (1,inf); abs err < 1e-5 post-scale — 1500x
    // under threshold. (Round-16 single-variable change vs the r15 green.)
    float u = 1.5957691216057308f * (x + 0.044715f * x * x * x);
    float ex = __expf(u);
#ifdef USE_RCPF
    return x * ex * __builtin_amdgcn_rcpf(ex + 1.0f);
#else
    return x * ex / (ex + 1.0f);
#endif
}

// ============== prep: verts -> float4 {x,y,z,sq} in d_ws ==============
__global__ void prep_kernel(const float* __restrict__ verts, float4* __restrict__ pv) {
    int i = blockIdx.x * blockDim.x + threadIdx.x;
    if (i >= BATCH * NPTS) return;
    float x = verts[3 * i], y = verts[3 * i + 1], z = verts[3 * i + 2];
    float sq = __fadd_rn(__fadd_rn(__fmul_rn(x, x), __fmul_rn(y, y)), __fmul_rn(z, z));
    pv[i] = make_float4(x, y, z, sq);
}

// ============== KNN v7: fast filter + unroll-4 scans + exact rescore ==============
__global__ __launch_bounds__(256, 4) void knn7_kernel(const float4* __restrict__ pv,
                                                      int* __restrict__ nbr_out_rows) {
    __shared__ float4 minv4[4][64];
    __shared__ float  bufD[4][4][CAP];
    __shared__ int    bufJ[4][4][CAP];

    const int tid = threadIdx.x, lane = tid & 63, wv = tid >> 6;
    const int pt0 = (blockIdx.x * 4 + wv) * 4;
    const int b = pt0 >> 13, i0 = pt0 & (NPTS - 1);
    const float4* P = pv + (size_t)b * NPTS;

    float4 sp[4];
    float ax[4], ay[4], az[4];
#pragma unroll
    for (int p = 0; p < 4; ++p) {
        sp[p] = P[i0 + p];
        ax[p] = -2.0f * sp[p].x; ay[p] = -2.0f * sp[p].y; az[p] = -2.0f * sp[p].z;
    }

    // ---- pass 1: fast per-lane min over first 4096 cands, 4 loads in flight ----
    float mn[4] = {INFINITY, INFINITY, INFINITY, INFINITY};
    for (int t = 0; t < 16; ++t) {
        float4 c0 = P[t * 256 + lane];
        float4 c1 = P[t * 256 + 64 + lane];
        float4 c2 = P[t * 256 + 128 + lane];
        float4 c3 = P[t * 256 + 192 + lane];
#pragma unroll
        for (int p = 0; p < 4; ++p) {
            float f0 = __fmaf_rn(ax[p], c0.x, __fmaf_rn(ay[p], c0.y, __fmaf_rn(az[p], c0.z, c0.w)));
            float f1 = __fmaf_rn(ax[p], c1.x, __fmaf_rn(ay[p], c1.y, __fmaf_rn(az[p], c1.z, c1.w)));
            float f2 = __fmaf_rn(ax[p], c2.x, __fmaf_rn(ay[p], c2.y, __fmaf_rn(az[p], c2.z, c2.w)));
            float f3 = __fmaf_rn(ax[p], c3.x, __fmaf_rn(ay[p], c3.y, __fmaf_rn(az[p], c3.z, c3.w)));
            mn[p] = fminf(fminf(fminf(mn[p], f0), fminf(f1, f2)), f3);   // exact: min reassoc-safe
        }
    }

    // ---- tau_p = 16th smallest lane-min + margin (rank-select) ----
    minv4[wv][lane] = make_float4(mn[0], mn[1], mn[2], mn[3]);
    int rk[4] = {0, 0, 0, 0};
    for (int mm = 0; mm < 64; ++mm) {
        float4 v = minv4[wv][mm];
        rk[0] += (v.x < mn[0]) || (v.x == mn[0] && mm < lane);
        rk[1] += (v.y < mn[1]) || (v.y == mn[1] && mm < lane);
        rk[2] += (v.z < mn[2]) || (v.z == mn[2] && mm < lane);
        rk[3] += (v.w < mn[3]) || (v.w == mn[3] && mm < lane);
    }
    float tau[4];
#pragma unroll
    for (int p = 0; p < 4; ++p) {
        u64 bal = __ballot(rk[p] == 15);
        int srcl = __ffsll(bal) - 1;
        tau[p] = __shfl(mn[p], srcl, 64) + KMARGIN;
    }

    // ---- pass 2: full scan (unroll 4), fast filter, two-level skip, compact ----
    int base[4] = {0, 0, 0, 0};
    for (int t = 0; t < 32; ++t) {
        float4 c[4];
#pragma unroll
        for (int k = 0; k < 4; ++k) c[k] = P[t * 256 + k * 64 + lane];
        bool pr[4][4];
        bool anyl = false;
#pragma unroll
        for (int k = 0; k < 4; ++k)
#pragma unroll
            for (int p = 0; p < 4; ++p) {
                float f = __fmaf_rn(ax[p], c[k].x,
                          __fmaf_rn(ay[p], c[k].y,
                          __fmaf_rn(az[p], c[k].z, c[k].w)));
                pr[k][p] = (f <= tau[p]);
                anyl |= pr[k][p];
            }
        if (__ballot(anyl) == 0ull) continue;
#pragma unroll
        for (int k = 0; k < 4; ++k) {
            u64 anyk = __ballot(pr[k][0] | pr[k][1] | pr[k][2] | pr[k][3]);
            if (anyk == 0ull) continue;
            int j = t * 256 + k * 64 + lane;
#pragma unroll
            for (int p = 0; p < 4; ++p) {
                u64 mk = __ballot(pr[k][p]);
                if (mk != 0ull) {
                    if (pr[k][p]) {
                        int pos = base[p] + (int)__popcll(mk & ((1ull << lane) - 1ull));
                        if (pos < CAP) bufJ[wv][p][pos] = j;
                    }
                    base[p] += (int)__popcll(mk);
                }
            }
        }
    }

    // ---- exact rescore + (d,j)-lex rank-select per point ----
#pragma unroll
    for (int p = 0; p < 4; ++p) {
        int ns = base[p]; ns = (ns > CAP) ? CAP : ns;   // >= 16 guaranteed
        float dloc[2]; int jloc[2];
#pragma unroll
        for (int slot = 0; slot < 2; ++slot) {
            int sidx = slot * 64 + lane;
            bool act = sidx < ns;
            int js = act ? bufJ[wv][p][sidx] : 0;
            float4 cc = P[js];
            float dot = __fmul_rn(sp[p].x, cc.x);
            dot = __fmaf_rn(sp[p].y, cc.y, dot);
            dot = __fmaf_rn(sp[p].z, cc.z, dot);
            float d = __fsub_rn(__fadd_rn(sp[p].w, cc.w), __fmul_rn(2.0f, dot));
            if (act) bufD[wv][p][sidx] = d;
            dloc[slot] = d; jloc[slot] = js;
        }
        int r0 = 0, r1 = 0;
        for (int mm = 0; mm < ns; ++mm) {
            float dm = bufD[wv][p][mm]; int jm = bufJ[wv][p][mm];
            r0 += (dm < dloc[0]) || (dm == dloc[0] && jm < jloc[0]);
            r1 += (dm < dloc[1]) || (dm == dloc[1] && jm < jloc[1]);
        }
        if (lane < ns && r0 < KNN)
            nbr_out_rows[(size_t)(pt0 + p) * 64 + r0] = jloc[0];
        if (64 + lane < ns && r1 < KNN)
            nbr_out_rows[(size_t)(pt0 + p) * 64 + r1] = jloc[1];
    }
}

// ============== KNN fallback (used only if ws too small) ==============
__global__ __launch_bounds__(256) void knn_kernel(const float* __restrict__ verts,
                                                  int* nbr_out_rows) {
    __shared__ float4 tilebuf[TILE];
    __shared__ float  bufD[4][CAP];
    __shared__ int    bufJ[4][CAP];

    const int tid = threadIdx.x, lane = tid & 63, wv = tid >> 6;
    const int pt = blockIdx.x * 4 + wv;
    const int b = pt >> 13, i = pt & (NPTS - 1);
    const float* vb = verts + (size_t)b * NPTS * 3;

    const float xi = vb[3 * i], yi = vb[3 * i + 1], zi = vb[3 * i + 2];
    const float sqi = __fadd_rn(__fadd_rn(__fmul_rn(xi, xi), __fmul_rn(yi, yi)),
                                __fmul_rn(zi, zi));

    float m_d = INFINITY;
    for (int t = 0; t < NPTS / TILE; ++t) {
        __syncthreads();
        for (int s = 0; s < TILE / 256; ++s) {
            int p = t * TILE + s * 256 + tid;
            float px = vb[3 * p], py = vb[3 * p + 1], pz = vb[3 * p + 2];
            float sq = __fadd_rn(__fadd_rn(__fmul_rn(px, px), __fmul_rn(py, py)),
                                 __fmul_rn(pz, pz));
            tilebuf[s * 256 + tid] = make_float4(px, py, pz, sq);
        }
        __syncthreads();
        for (int it = 0; it < TILE / 64; ++it) {
            float4 c = tilebuf[it * 64 + lane];
            float dot = __fmul_rn(xi, c.x);
            dot = __fmaf_rn(yi, c.y, dot);
            dot = __fmaf_rn(zi, c.z, dot);
            float d = __fsub_rn(__fadd_rn(sqi, c.w), __fmul_rn(2.0f, dot));
            m_d = fminf(m_d, d);
        }
    }
    __shared__ float minv[4][64];
    minv[wv][lane] = m_d;
    __syncthreads();
    int rnk = 0;
    for (int mm = 0; mm < 64; ++mm) {
        float vm = minv[wv][mm];
        rnk += (vm < m_d) || (vm == m_d && mm < lane);
    }
    u64 bal = __ballot(rnk == 15);
    float tau = __shfl(m_d, __ffsll(bal) - 1, 64);

    int base = 0;
    for (int t = 0; t < NPTS / TILE; ++t) {
        __syncthreads();
        for (int s = 0; s < TILE / 256; ++s) {
            int p = t * TILE + s * 256 + tid;
            float px = vb[3 * p], py = vb[3 * p + 1], pz = vb[3 * p + 2];
            float sq = __fadd_rn(__fadd_rn(__fmul_rn(px, px), __fmul_rn(py, py)),
                                 __fmul_rn(pz, pz));
            tilebuf[s * 256 + tid] = make_float4(px, py, pz, sq);
        }
        __syncthreads();
        for (int it = 0; it < TILE / 64; ++it) {
            int jl = it * 64 + lane;
            float4 c = tilebuf[jl];
            float dot = __fmul_rn(xi, c.x);
            dot = __fmaf_rn(yi, c.y, dot);
            dot = __fmaf_rn(zi, c.z, dot);
            float d = __fsub_rn(__fadd_rn(sqi, c.w), __fmul_rn(2.0f, dot));
            bool pred = (d <= tau);
            u64 mask = __ballot(pred);
            if (pred) {
                int pos = base + (int)__popcll(mask & ((1ull << lane) - 1ull));
                if (pos < CAP) { bufD[wv][pos] = d; bufJ[wv][pos] = t * TILE + jl; }
            }
            base += (int)__popcll(mask);
        }
    }
    int ns = (base > CAP) ? CAP : base;
    __syncthreads();
#pragma unroll
    for (int slot = 0; slot < 2; ++slot) {
        int sidx = slot * 64 + lane;
        if (sidx < ns) {
            float ds = bufD[wv][sidx];
            int   js = bufJ[wv][sidx];
            int rank = 0;
            for (int mm = 0; mm < ns; ++mm) {
                float dm = bufD[wv][mm];
                int   jm = bufJ[wv][mm];
                rank += (dm < ds) || (dm == ds && jm < js);
            }
            if (rank < KNN) nbr_out_rows[(size_t)pt * 64 + rank] = js;
        }
    }
}

// ============ edge4: barrier-free MFMA edge MLP + mean + point MLP ============
// r11/r15 green kernel; only gelu_t changed (rcpf). (256,2): no spill.
__global__ __launch_bounds__(256, 2) void edge4_kernel(
    const float* __restrict__ verts, const float* __restrict__ feats,
    const float* __restrict__ W1, const float* __restrict__ b1,
    const float* __restrict__ g1, const float* __restrict__ be1,
    const float* __restrict__ W2, const float* __restrict__ b2,
    const float* __restrict__ Wo1, const float* __restrict__ bo1,
    const float* __restrict__ go_, const float* __restrict__ beo,
    const float* __restrict__ Wo2, const float* __restrict__ bo2,
    float* out)   // rows hold knn idx on entry; final output on exit
{
    __shared__ u16 EPw[4][4][64][8];    // 16 KB: per-wave E/P A-frag region
    __shared__ u16 W1F[3][8][64][8];    // 24 KB (phase2: Wo1 frags in kt 0..1)
    __shared__ float b1s[HID], g1s[HID], be1s[HID];
    __shared__ float b2s[COUT];
    __shared__ float meansh[16][68];    // 4.25 KB; phase2: staging for out rows

    const int tid  = threadIdx.x;
    const int lane = tid & 63, wv = tid >> 6;
    const int quad = lane >> 4, n16 = lane & 15;

    // ---- stage W1 as B-fragments ----
    for (int s = tid; s < 3 * 8 * 64; s += 256) {
        int kt = s >> 9, nt = (s >> 6) & 7, ln = s & 63;
        int q = ln >> 4, nn = ln & 15;
        int col = nt * 16 + nn;
        union { bf16x8 v; unsigned u[4]; } pk;
#pragma unroll
        for (int jj = 0; jj < 4; ++jj) {
            int k0 = kt * 32 + q * 8 + jj * 2;
            float a  = (k0     < EIN) ? W1[(size_t)k0 * HID + col]       : 0.0f;
            float bq = (k0 + 1 < EIN) ? W1[(size_t)(k0 + 1) * HID + col] : 0.0f;
            pk.u[jj] = pk2(a, bq);
        }
        *(bf16x8*)&W1F[kt][nt][ln][0] = pk.v;
    }
    if (tid < HID) { b1s[tid] = b1[tid]; g1s[tid] = g1[tid]; be1s[tid] = be1[tid]; }
    if (tid < COUT) b2s[tid] = b2[tid];

    // ---- W2 as B-fragments in registers (64 VGPR) ----
    bf16x8 w2r[4][4];
#pragma unroll
    for (int kt2 = 0; kt2 < 4; ++kt2)
#pragma unroll
        for (int nt2 = 0; nt2 < 4; ++nt2) {
            union { bf16x8 v; unsigned u[4]; } pk;
#pragma unroll
            for (int jj = 0; jj < 4; ++jj) {
                int k0 = kt2 * 32 + quad * 8 + jj * 2;
                int o = nt2 * 16 + n16;
                pk.u[jj] = pk2(W2[(size_t)k0 * COUT + o],
                               W2[(size_t)(k0 + 1) * COUT + o]);
            }
            w2r[kt2][nt2] = pk.v;
        }
    __syncthreads();   // W1F + biases visible to all waves

    const int ptb = blockIdx.x * 16;
    const int bb  = ptb >> 13;
    const float* fb  = feats + (size_t)bb * NPTS * CIN;
    const float* vbk = verts + (size_t)bb * NPTS * 3;
    const int ptw = ptb + wv * 4;              // this wave's 4 points
    const int ipw = ptw & (NPTS - 1);

    // hoisted LN operands (point-independent)
    float b1v[8], g1v[8], bev[8];
#pragma unroll
    for (int nt = 0; nt < 8; ++nt) {
        b1v[nt] = b1s[nt * 16 + n16];
        g1v[nt] = g1s[nt * 16 + n16];
        bev[nt] = be1s[nt * 16 + n16];
    }

    const int k16 = lane & 15;
    const int qq  = lane >> 4;

    int jnv[4];
#pragma unroll
    for (int pp = 0; pp < 4; ++pp)
        jnv[pp] = ((const int*)out)[(size_t)(ptw + pp) * 64 + k16];

#pragma unroll
    for (int pp = 0; pp < 4; ++pp) {
        const int jn  = jnv[pp];
        const int ipn = ipw + pp;

        // ---- gather + pack + store E (3 b128 per lane, wave-local) ----
        {
            const float* nsrc = fb + (size_t)jn * CIN + qq * 8;
            float4 nA = *(const float4*)nsrc, nB = *(const float4*)(nsrc + 4);
            const float* ssrc = fb + (size_t)ipn * CIN + qq * 8;
            float4 sA = *(const float4*)ssrc, sB = *(const float4*)(ssrc + 4);

            union { bf16x8 v; unsigned u[4]; } e0, e1, e2;
            e0.u[0] = pk2(nA.x, nA.y); e0.u[1] = pk2(nA.z, nA.w);
            e0.u[2] = pk2(nB.x, nB.y); e0.u[3] = pk2(nB.z, nB.w);
            e1.u[0] = pk2(sA.x, sA.y); e1.u[1] = pk2(sA.z, sA.w);
            e1.u[2] = pk2(sB.x, sB.y); e1.u[3] = pk2(sB.z, sB.w);
            e2.u[0] = e2.u[1] = e2.u[2] = e2.u[3] = 0u;
            if (qq == 0) {
                float rx = vbk[3 * jn]     - vbk[3 * ipn];
                float ry = vbk[3 * jn + 1] - vbk[3 * ipn + 1];
                float rz = vbk[3 * jn + 2] - vbk[3 * ipn + 2];
                e2.u[0] = pk2(rx, ry); e2.u[1] = pk2(rz, 0.0f);
            }
            *(bf16x8*)&EPw[wv][0][lane][0] = e0.v;
            *(bf16x8*)&EPw[wv][1][lane][0] = e1.v;
            *(bf16x8*)&EPw[wv][2][lane][0] = e2.v;
        }

        // ---- GEMM1: D1[16 edges][128 hid] ----
        f32x4 acc[8];
#pragma unroll
        for (int nt = 0; nt < 8; ++nt) acc[nt] = (f32x4){0.f, 0.f, 0.f, 0.f};
#pragma unroll
        for (int kt = 0; kt < 3; ++kt) {
            bf16x8 a = *(bf16x8*)&EPw[wv][kt][lane][0];
#pragma unroll
            for (int nt = 0; nt < 8; ++nt) {
                bf16x8 bfr = *(bf16x8*)&W1F[kt][nt][lane][0];
                acc[nt] = __builtin_amdgcn_mfma_f32_16x16x32_bf16(a, bfr, acc[nt], 0, 0, 0);
            }
        }

        // ---- bias + LN (16-lane groups) ----
        float s1[4] = {0,0,0,0}, s2[4] = {0,0,0,0};
#pragma unroll
        for (int nt = 0; nt < 8; ++nt)
#pragma unroll
            for (int r = 0; r < 4; ++r) {
                float x = acc[nt][r] + b1v[nt];
                s1[r] += x; s2[r] += x * x;
            }
#pragma unroll
        for (int r = 0; r < 4; ++r) {
#pragma unroll
            for (int off = 1; off < 16; off <<= 1) {
                s1[r] += __shfl_xor(s1[r], off, 64);
                s2[r] += __shfl_xor(s2[r], off, 64);
            }
        }
        float mu[4], rs[4];
#pragma unroll
        for (int r = 0; r < 4; ++r) {
            mu[r] = s1[r] * (1.0f / HID);
            float var = s2[r] * (1.0f / HID) - mu[r] * mu[r];
            rs[r] = rsqrtf(var + 1e-5f);
        }

        // ---- GELU + pack into A-frag layout (P over EPw[wv]) ----
#pragma unroll
        for (int nt = 0; nt < 8; ++nt) {
            int kt2 = nt >> 1;
            int q2  = (nt * 2 + (n16 >> 3)) & 3;
            int jj  = n16 & 7;
#pragma unroll
            for (int r = 0; r < 4; ++r) {
                float x  = acc[nt][r] + b1v[nt];
                float xn = (x - mu[r]) * rs[r] * g1v[nt] + bev[nt];
                EPw[wv][kt2][quad * 4 + r + 16 * q2][jj] = (u16)f2b(gelu_t(xn));
            }
        }

        // ---- GEMM2: D2[16 edges][64 out] ----
        f32x4 acc2[4];
#pragma unroll
        for (int nt2 = 0; nt2 < 4; ++nt2) acc2[nt2] = (f32x4){0.f, 0.f, 0.f, 0.f};
#pragma unroll
        for (int kt2 = 0; kt2 < 4; ++kt2) {
            bf16x8 a2 = *(bf16x8*)&EPw[wv][kt2][lane][0];
#pragma unroll
            for (int nt2 = 0; nt2 < 4; ++nt2)
                acc2[nt2] = __builtin_amdgcn_mfma_f32_16x16x32_bf16(a2, w2r[kt2][nt2], acc2[nt2], 0, 0, 0);
        }

        // ---- mean over 16 edges (+b2) -> meansh ----
#pragma unroll
        for (int nt2 = 0; nt2 < 4; ++nt2) {
            float cs = acc2[nt2][0] + acc2[nt2][1] + acc2[nt2][2] + acc2[nt2][3];
            cs += __shfl_xor(cs, 16, 64);
            cs += __shfl_xor(cs, 32, 64);
            if (quad == 0) {
                int o = nt2 * 16 + n16;
                meansh[wv * 4 + pp][o] = cs * (1.0f / KNN) + b2s[o];
            }
        }
    }

    // ======== phase 2: point MLP (MFMA) for the block's 16 points ========
    __syncthreads();   // all means written; safe to overlay W1F/biases

    for (int s = tid; s < 2 * 8 * 64; s += 256) {   // Wo1 B-frags (K=64)
        int kt = s >> 9, nt = (s >> 6) & 7, ln = s & 63;
        int q = ln >> 4, nn = ln & 15;
        int col = nt * 16 + nn;
        union { bf16x8 v; unsigned u[4]; } pk;
#pragma unroll
        for (int jj = 0; jj < 4; ++jj) {
            int k0 = kt * 32 + q * 8 + jj * 2;
            pk.u[jj] = pk2(Wo1[(size_t)k0 * HID + col],
                           Wo1[(size_t)(k0 + 1) * HID + col]);
        }
        *(bf16x8*)&W1F[kt][nt][ln][0] = pk.v;
    }
    if (tid < HID) { b1s[tid] = bo1[tid]; g1s[tid] = go_[tid]; be1s[tid] = beo[tid]; }
    if (tid < COUT) b2s[tid] = bo2[tid];
#pragma unroll
    for (int kt2 = 0; kt2 < 4; ++kt2)
#pragma unroll
        for (int nt2 = 0; nt2 < 4; ++nt2) {
            union { bf16x8 v; unsigned u[4]; } pk;
#pragma unroll
            for (int jj = 0; jj < 4; ++jj) {
                int k0 = kt2 * 32 + quad * 8 + jj * 2;
                int o = nt2 * 16 + n16;
                pk.u[jj] = pk2(Wo2[(size_t)k0 * COUT + o],
                               Wo2[(size_t)(k0 + 1) * COUT + o]);
            }
            w2r[kt2][nt2] = pk.v;
        }
    __syncthreads();

    if (wv == 0) {
        bf16x8 af[2];
#pragma unroll
        for (int kt = 0; kt < 2; ++kt) {
            const float* mrow = &meansh[n16][kt * 32 + quad * 8];
            float4 A = *(const float4*)mrow, B4 = *(const float4*)(mrow + 4);
            union { bf16x8 v; unsigned u[4]; } pk;
            pk.u[0] = pk2(A.x, A.y); pk.u[1] = pk2(A.z, A.w);
            pk.u[2] = pk2(B4.x, B4.y); pk.u[3] = pk2(B4.z, B4.w);
            af[kt] = pk.v;
        }

        f32x4 acc[8];
#pragma unroll
        for (int nt = 0; nt < 8; ++nt) acc[nt] = (f32x4){0.f, 0.f, 0.f, 0.f};
#pragma unroll
        for (int kt = 0; kt < 2; ++kt)
#pragma unroll
            for (int nt = 0; nt < 8; ++nt) {
                bf16x8 bfr = *(bf16x8*)&W1F[kt][nt][lane][0];
                acc[nt] = __builtin_amdgcn_mfma_f32_16x16x32_bf16(af[kt], bfr, acc[nt], 0, 0, 0);
            }

        float pb1[8], pg1[8], pbe[8];
#pragma unroll
        for (int nt = 0; nt < 8; ++nt) {
            pb1[nt] = b1s[nt * 16 + n16];
            pg1[nt] = g1s[nt * 16 + n16];
            pbe[nt] = be1s[nt * 16 + n16];
        }
        float s1[4] = {0,0,0,0}, s2[4] = {0,0,0,0};
#pragma unroll
        for (int nt = 0; nt < 8; ++nt)
#pragma unroll
            for (int r = 0; r < 4; ++r) {
                float x = acc[nt][r] + pb1[nt];
                s1[r] += x; s2[r] += x * x;
            }
#pragma unroll
        for (int r = 0; r < 4; ++r) {
#pragma unroll
            for (int off = 1; off < 16; off <<= 1) {
                s1[r] += __shfl_xor(s1[r], off, 64);
                s2[r] += __shfl_xor(s2[r], off, 64);
            }
        }
#pragma unroll
        for (int nt = 0; nt < 8; ++nt) {
            int kt2 = nt >> 1;
            int q2  = (nt * 2 + (n16 >> 3)) & 3;
            int jj  = n16 & 7;
#pragma unroll
            for (int r = 0; r < 4; ++r) {
                float mu = s1[r] * (1.0f / HID);
                float var = s2[r] * (1.0f / HID) - mu * mu;
                float rs = rsqrtf(var + 1e-5f);
                float x  = acc[nt][r] + pb1[nt];
                float xn = (x - mu) * rs * pg1[nt] + pbe[nt];
                EPw[0][kt2][quad * 4 + r + 16 * q2][jj] = (u16)f2b(gelu_t(xn));
            }
        }

        f32x4 acc2[4];
#pragma unroll
        for (int nt2 = 0; nt2 < 4; ++nt2) acc2[nt2] = (f32x4){0.f, 0.f, 0.f, 0.f};
#pragma unroll
        for (int kt2 = 0; kt2 < 4; ++kt2) {
            bf16x8 a2 = *(bf16x8*)&EPw[0][kt2][lane][0];
#pragma unroll
            for (int nt2 = 0; nt2 < 4; ++nt2)
                acc2[nt2] = __builtin_amdgcn_mfma_f32_16x16x32_bf16(a2, w2r[kt2][nt2], acc2[nt2], 0, 0, 0);
        }

        // stage final rows into meansh (means fully consumed by af above)
#pragma unroll
        for (int nt2 = 0; nt2 < 4; ++nt2) {
            int o = nt2 * 16 + n16;
#pragma unroll
            for (int r = 0; r < 4; ++r)
                meansh[quad * 4 + r][o] = acc2[nt2][r] + b2s[o];
        }
    }
    __syncthreads();

    // coalesced float4 store: thread -> (point = tid>>4, 4 channels)
    {
        int p = tid >> 4, c = (tid & 15) * 4;
        float4 v = *(const float4*)&meansh[p][c];
        *(float4*)&out[(size_t)(ptb + p) * 64 + c] = v;
    }
}

extern "C" void kernel_launch(void* const* d_in, const int* in_sizes, int n_in,
                              void* d_out, int out_size, void* d_ws, size_t ws_size,
                              hipStream_t stream) {
    const float* verts = (const float*)d_in[0];
    const float* feats = (const float*)d_in[1];
    const float* W1  = (const float*)d_in[2];
    const float* b1  = (const float*)d_in[3];
    const float* g1  = (const float*)d_in[4];
    const float* be1 = (const float*)d_in[5];
    const float* W2  = (const float*)d_in[6];
    const float* b2  = (const float*)d_in[7];
    const float* Wo1 = (const float*)d_in[8];
    const float* bo1 = (const float*)d_in[9];
    const float* go_ = (const float*)d_in[10];
    const float* beo = (const float*)d_in[11];
    const float* Wo2 = (const float*)d_in[12];
    const float* bo2 = (const float*)d_in[13];
    float* out = (float*)d_out;

    (void)in_sizes; (void)n_in; (void)out_size;

    const size_t pv_bytes = (size_t)BATCH * NPTS * sizeof(float4);  // 256 KB
    if (ws_size >= pv_bytes) {
        float4* pv = (float4*)d_ws;
        prep_kernel<<<(BATCH * NPTS + 255) / 256, 256, 0, stream>>>(verts, pv);
        knn7_kernel<<<(BATCH * NPTS) / 16, 256, 0, stream>>>(pv, (int*)out);
    } else {
        knn_kernel<<<(BATCH * NPTS) / 4, 256, 0, stream>>>(verts, (int*)out);
    }
    edge4_kernel<<<(BATCH * NPTS) / 16, 256, 0, stream>>>(
        verts, feats, W1, b1, g1, be1, W2, b2,
        Wo1, bo1, go_, beo, Wo2, bo2, out);
}